// Round 1
// baseline (189.963 us; speedup 1.0000x reference)
//
#include <hip/hip_runtime.h>
#include <math.h>

#define MUL 8
#define HID 16
#define NB 10

// Kernel A: zero the scalar output and reduce W2 (16 x 256) over its trailing
// v-dimension into W2red (16 x 32), folding in the 1/sqrt(HID)=0.25 scale.
__global__ void prep_kernel(const float* __restrict__ W2,
                            float* __restrict__ W2red,
                            float* __restrict__ out) {
    int t = threadIdx.x;
    if (t == 0) out[0] = 0.0f;
    if (t < HID * 32) {
        int j  = t >> 5;   // hidden index 0..15
        int cu = t & 31;   // c*8+u index 0..31
        const float* p = W2 + j * 256 + cu * 8;
        float s = 0.0f;
#pragma unroll
        for (int v = 0; v < 8; ++v) s += p[v];
        W2red[t] = 0.25f * s;
    }
}

// Kernel B: one edge per thread; per-edge MLP (10->16->32 reduced) + analytic
// channel-sum contraction; block reduction; one atomicAdd per block.
__global__ __launch_bounds__(256) void edge_kernel(
    const float* __restrict__ X,      // N x 32 node features
    const float* __restrict__ EV,     // E x 3 edge vectors
    const float* __restrict__ W1,     // 10 x 16
    const float* __restrict__ W2red,  // 16 x 32 (precomputed, includes 0.25)
    const int*   __restrict__ SRC,    // E
    float* __restrict__ out, int E)
{
    __shared__ float sW1[NB * HID];
    __shared__ float sW2[HID * 32];
    int tid = threadIdx.x;
    for (int i = tid; i < NB * HID; i += 256) sW1[i] = W1[i];
    for (int i = tid; i < HID * 32; i += 256) sW2[i] = W2red[i];
    __syncthreads();

    int e = blockIdx.x * 256 + tid;
    float contrib = 0.0f;
    if (e < E) {
        float ex = EV[3 * e], ey = EV[3 * e + 1], ez = EV[3 * e + 2];
        float r = sqrtf(ex * ex + ey * ey + ez * ez);
        float inv_r = 1.0f / r;
        float ux = ex * inv_r, uy = ey * inv_r, uz = ez * inv_r;

        // soft one-hot basis; values[i] = 3(i+1)/11, step = 3/11.
        // (the sqrt(10) on emb cancels the /sqrt(10) before W1 -> omitted)
        float f[NB];
        const float step = 3.0f / 11.0f;
#pragma unroll
        for (int i = 0; i < NB; ++i) {
            float diff  = (r - step * (float)(i + 1)) / step;
            float denom = 1.0f - diff * diff;
            f[i] = (denom > 0.0f) ? 1.14136f * expf(2.0f - 2.0f / denom) : 0.0f;
        }

        // h = relu(f @ W1) * sqrt(2)
        float h[HID];
#pragma unroll
        for (int j = 0; j < HID; ++j) {
            float a = 0.0f;
#pragma unroll
            for (int i = 0; i < NB; ++i) a += f[i] * sW1[i * HID + j];
            h[j] = (a > 0.0f) ? a * 1.41421356237f : 0.0f;
        }

        // wr[c*8+u] = sum_v w[c][u][v]  (0.25 scale already folded in sW2)
        float wr[32];
#pragma unroll
        for (int c = 0; c < 32; ++c) {
            float a = 0.0f;
#pragma unroll
            for (int j = 0; j < HID; ++j) a += h[j] * sW2[j * 32 + c];
            wr[c] = a;
        }

        const float* xp = X + (long)SRC[e] * (4 * MUL);
        float U = ux + uy + uz;
        const float pw0 = 0.25f;            // sqrt(1/(2*MUL))
        const float pw1 = 0.43301270189f;   // sqrt(3/(2*MUL))
        const float i3  = 0.57735026919f;   // 1/sqrt(3)
        float acc = 0.0f;
#pragma unroll
        for (int u = 0; u < MUL; ++u) {
            float s  = xp[u];
            float vx = xp[MUL + 3 * u + 0];
            float vy = xp[MUL + 3 * u + 1];
            float vz = xp[MUL + 3 * u + 2];
            float d  = vx * ux + vy * uy + vz * uz;  // v[u] . unit
            float V  = vx + vy + vz;
            acc += pw0 * (wr[u] * s + wr[8 + u] * d)
                 + pw1 * (wr[16 + u] * s * U + i3 * wr[24 + u] * V);
        }
        contrib = acc * 0.25f;  // / sqrt(NUM_NEIGHBORS=16)
    }

    // wave64 shuffle reduce, then cross-wave LDS reduce, one atomic per block
#pragma unroll
    for (int off = 32; off > 0; off >>= 1)
        contrib += __shfl_down(contrib, off, 64);
    __shared__ float wsum[4];
    int lane = tid & 63, w = tid >> 6;
    if (lane == 0) wsum[w] = contrib;
    __syncthreads();
    if (tid == 0) {
        float s = wsum[0] + wsum[1] + wsum[2] + wsum[3];
        atomicAdd(out, s);
    }
}

extern "C" void kernel_launch(void* const* d_in, const int* in_sizes, int n_in,
                              void* d_out, int out_size, void* d_ws, size_t ws_size,
                              hipStream_t stream) {
    const float* X   = (const float*)d_in[0];  // input_features (N,32)
    const float* EV  = (const float*)d_in[1];  // edge_vec (E,3)
    const float* W1  = (const float*)d_in[2];  // (10,16)
    const float* W2  = (const float*)d_in[3];  // (16,256)
    const int*   SRC = (const int*)d_in[4];    // edge_src (E)
    // d_in[5] = edge_dst (unused: segment_sum + full sum == plain edge sum)
    // d_in[6] = num_nodes (unused)
    int E = in_sizes[4];

    float* W2red = (float*)d_ws;  // 512 floats
    float* out   = (float*)d_out;

    prep_kernel<<<1, 512, 0, stream>>>(W2, W2red, out);
    int blocks = (E + 255) / 256;
    edge_kernel<<<blocks, 256, 0, stream>>>(X, EV, W1, W2red, SRC, out, E);
}

// Round 2
// 125.102 us; speedup vs baseline: 1.5185x; 1.5185x over previous
//
#include <hip/hip_runtime.h>
#include <math.h>

#define MUL 8
#define HID 16
#define NB 10

// Kernel A: zero out; build scaled reduced weights in d_ws:
//   ws[0..511]  = W2red[j][cu] = group_scale(c) * 0.0625 * sum_v W2[j][cu*8+v]
//                 (0.25 = 1/sqrt(HID), 0.25 = 1/sqrt(NUM_NEIGHBORS), group scales
//                  pw0, pw0, pw1, pw1/sqrt(3) folded in)
//   ws[512..671] = W1s = sqrt(2) * W1   (relu(a)*sqrt2 == relu(a*sqrt2))
__global__ void prep_kernel(const float* __restrict__ W2,
                            const float* __restrict__ W1,
                            float* __restrict__ ws,
                            float* __restrict__ out) {
    int t = threadIdx.x;
    if (t == 0) out[0] = 0.0f;
    if (t < HID * 32) {
        int j  = t >> 5;
        int cu = t & 31;
        int c  = cu >> 3;
        const float pw0 = 0.25f;            // sqrt(1/16)
        const float pw1 = 0.43301270189f;   // sqrt(3/16)
        const float i3  = 0.57735026919f;   // 1/sqrt(3)
        float gs = (c < 2) ? pw0 : ((c == 2) ? pw1 : pw1 * i3);
        const float* p = W2 + j * 256 + cu * 8;
        float s = 0.0f;
#pragma unroll
        for (int v = 0; v < 8; ++v) s += p[v];
        ws[t] = s * 0.0625f * gs;
    }
    if (t < NB * HID) ws[512 + t] = W1[t] * 1.41421356237f;
}

// Kernel B: one edge per thread. Weights read from GLOBAL with uniform
// constant offsets -> compiler emits s_load into SGPRs (scalar cache),
// FMAs take SGPR operands. No LDS on the weight path.
__global__ __launch_bounds__(256, 6) void edge_kernel(
    const float* __restrict__ X,     // N x 32
    const float* __restrict__ EV,    // E x 3
    const int*   __restrict__ SRC,   // E
    const float* __restrict__ W2r,   // 16 x 32 scaled (ws)
    const float* __restrict__ W1s,   // 10 x 16 scaled (ws+512)
    float* __restrict__ out, int E)
{
    int tid = threadIdx.x;
    int e = blockIdx.x * 256 + tid;
    float contrib = 0.0f;
    if (e < E) {
        float ex = EV[3 * e], ey = EV[3 * e + 1], ez = EV[3 * e + 2];
        float r = sqrtf(ex * ex + ey * ey + ez * ez);
        float inv_r = 1.0f / r;
        float ux = ex * inv_r, uy = ey * inv_r, uz = ez * inv_r;
        float U = ux + uy + uz;

        // --- 2-sparse soft one-hot: only bumps floor(q)-1 and floor(q) can
        // be nonzero (|diff| < 1). Skipped terms are exact zeros.
        const float inv_step = 11.0f / 3.0f;   // 1/step, step = 3/11
        float q = r * inv_step;
        int qi = (int)floorf(q);
        int ia = qi - 1, ib = qi;
        float diffa = q - (float)(ia + 1);     // in [0,1)
        float diffb = q - (float)(ib + 1);     // in [-1,0)
        float dena = 1.0f - diffa * diffa;     // (0,1]
        float denb = 1.0f - diffb * diffb;     // [0,1] ; 0 -> exp(-inf)=0
        bool va = (ia >= 0) & (ia < NB);
        bool vb = (ib >= 0) & (ib < NB);
        float fa = va ? 1.14136f * expf(2.0f - 2.0f / dena) : 0.0f;
        float fb = vb ? 1.14136f * expf(2.0f - 2.0f / denb) : 0.0f;
        int ica = min(max(ia, 0), NB - 1);
        int icb = min(max(ib, 0), NB - 1);
        const float* ra = W1s + ica * HID;   // per-lane gather, L1-resident
        const float* rb = W1s + icb * HID;

        float h[HID];
#pragma unroll
        for (int j = 0; j < HID; ++j) {
            float a = fa * ra[j] + fb * rb[j];
            h[j] = (a > 0.0f) ? a : 0.0f;
        }

        // --- gather node features, reduce v to d (dot unit) and V (comp sum)
        const float* xp = X + (long)SRC[e] * (4 * MUL);
        float s[MUL], xv[24];
#pragma unroll
        for (int k = 0; k < 2; ++k) {
            float4 t = ((const float4*)xp)[k];
            s[4 * k] = t.x; s[4 * k + 1] = t.y; s[4 * k + 2] = t.z; s[4 * k + 3] = t.w;
        }
#pragma unroll
        for (int k = 0; k < 6; ++k) {
            float4 t = ((const float4*)(xp + 8))[k];
            xv[4 * k] = t.x; xv[4 * k + 1] = t.y; xv[4 * k + 2] = t.z; xv[4 * k + 3] = t.w;
        }
        float d[MUL], V[MUL];
#pragma unroll
        for (int u = 0; u < MUL; ++u) {
            float vx = xv[3 * u], vy = xv[3 * u + 1], vz = xv[3 * u + 2];
            d[u] = vx * ux + vy * uy + vz * uz;
            V[u] = vx + vy + vz;
        }

        // --- contraction: acc = sum_j h[j] * (A + B + U*C + D)
        // W2r reads are uniform constant offsets -> s_load / SGPR operands.
        float acc = 0.0f;
#pragma unroll
        for (int j = 0; j < HID; ++j) {
            const float* w = W2r + j * 32;
            float A = 0.0f, B = 0.0f, C = 0.0f, D = 0.0f;
#pragma unroll
            for (int u = 0; u < MUL; ++u) {
                A += w[u]      * s[u];
                B += w[8 + u]  * d[u];
                C += w[16 + u] * s[u];
                D += w[24 + u] * V[u];
            }
            acc += h[j] * (A + B + U * C + D);
        }
        contrib = acc;
    }

    // wave64 shuffle reduce, cross-wave LDS reduce, one atomic per block
#pragma unroll
    for (int off = 32; off > 0; off >>= 1)
        contrib += __shfl_down(contrib, off, 64);
    __shared__ float wsum[4];
    int lane = tid & 63, w = tid >> 6;
    if (lane == 0) wsum[w] = contrib;
    __syncthreads();
    if (tid == 0) {
        float ssum = wsum[0] + wsum[1] + wsum[2] + wsum[3];
        atomicAdd(out, ssum);
    }
}

extern "C" void kernel_launch(void* const* d_in, const int* in_sizes, int n_in,
                              void* d_out, int out_size, void* d_ws, size_t ws_size,
                              hipStream_t stream) {
    const float* X   = (const float*)d_in[0];
    const float* EV  = (const float*)d_in[1];
    const float* W1  = (const float*)d_in[2];
    const float* W2  = (const float*)d_in[3];
    const int*   SRC = (const int*)d_in[4];
    int E = in_sizes[4];

    float* ws  = (float*)d_ws;   // 512 + 160 floats
    float* out = (float*)d_out;

    prep_kernel<<<1, 512, 0, stream>>>(W2, W1, ws, out);
    int blocks = (E + 255) / 256;
    edge_kernel<<<blocks, 256, 0, stream>>>(X, EV, SRC, ws, ws + 512, out, E);
}

// Round 3
// 120.952 us; speedup vs baseline: 1.5706x; 1.0343x over previous
//
#include <hip/hip_runtime.h>
#include <math.h>

#define MUL 8
#define HID 16
#define NB 10

// Kernel A: zero out; build scaled reduced weights in d_ws:
//   ws[0..511]  = W2red[j][cu] = group_scale(c) * 0.0625 * sum_v W2[j][cu*8+v]
//   ws[512..671] = W1s = sqrt(2) * W1
__global__ void prep_kernel(const float* __restrict__ W2,
                            const float* __restrict__ W1,
                            float* __restrict__ ws,
                            float* __restrict__ out) {
    int t = threadIdx.x;
    if (t == 0) out[0] = 0.0f;
    if (t < HID * 32) {
        int j  = t >> 5;
        int cu = t & 31;
        int c  = cu >> 3;
        const float pw0 = 0.25f;            // sqrt(1/16)
        const float pw1 = 0.43301270189f;   // sqrt(3/16)
        const float i3  = 0.57735026919f;   // 1/sqrt(3)
        float gs = (c < 2) ? pw0 : ((c == 2) ? pw1 : pw1 * i3);
        const float* p = W2 + j * 256 + cu * 8;
        float s = 0.0f;
#pragma unroll
        for (int v = 0; v < 8; ++v) s += p[v];
        ws[t] = s * 0.0625f * gs;
    }
    if (t < NB * HID) ws[512 + t] = W1[t] * 1.41421356237f;
}

// basis + hidden layer: depends only on r (no X dependency -> schedulable
// while X gathers are in flight)
__device__ __forceinline__ void basis_h(float r, const float* __restrict__ W1s,
                                        float h[HID]) {
    const float inv_step = 11.0f / 3.0f;   // step = 3/11
    float q = r * inv_step;
    int qi = (int)floorf(q);
    int ia = qi - 1, ib = qi;
    float diffa = q - (float)(ia + 1);     // [0,1)
    float diffb = q - (float)(ib + 1);     // [-1,0)
    float dena = 1.0f - diffa * diffa;     // (0,1]
    float denb = 1.0f - diffb * diffb;     // [0,1]; 0 -> exp(-inf)=0
    bool va = (ia >= 0) & (ia < NB);
    bool vb = (ib >= 0) & (ib < NB);
    float fa = va ? 1.14136f * __expf(2.0f - 2.0f / dena) : 0.0f;
    float fb = vb ? 1.14136f * __expf(2.0f - 2.0f / denb) : 0.0f;
    int ica = min(max(ia, 0), NB - 1);
    int icb = min(max(ib, 0), NB - 1);
    const float* ra = W1s + ica * HID;
    const float* rb = W1s + icb * HID;
#pragma unroll
    for (int j = 0; j < HID; ++j) {
        float a = fa * ra[j] + fb * rb[j];
        h[j] = (a > 0.0f) ? a : 0.0f;
    }
}

// contraction given pre-loaded X registers
__device__ __forceinline__ float edge_acc(const float h[HID], const float4 x[8],
                                          float ux, float uy, float uz, float U,
                                          const float* __restrict__ W2r) {
    float s[MUL] = {x[0].x, x[0].y, x[0].z, x[0].w,
                    x[1].x, x[1].y, x[1].z, x[1].w};
    float vv[24];
#pragma unroll
    for (int k = 0; k < 6; ++k) {
        vv[4 * k + 0] = x[2 + k].x;
        vv[4 * k + 1] = x[2 + k].y;
        vv[4 * k + 2] = x[2 + k].z;
        vv[4 * k + 3] = x[2 + k].w;
    }
    float d[MUL], V[MUL];
#pragma unroll
    for (int u = 0; u < MUL; ++u) {
        float vx = vv[3 * u], vy = vv[3 * u + 1], vz = vv[3 * u + 2];
        d[u] = vx * ux + vy * uy + vz * uz;
        V[u] = vx + vy + vz;
    }
    float acc = 0.0f;
#pragma unroll
    for (int j = 0; j < HID; ++j) {
        const float* w = W2r + j * 32;   // uniform offsets -> s_load
        float A = 0.0f, B = 0.0f, C = 0.0f, D = 0.0f;
#pragma unroll
        for (int u = 0; u < MUL; ++u) {
            A += w[u]      * s[u];
            B += w[8 + u]  * d[u];
            C += w[16 + u] * s[u];
            D += w[24 + u] * V[u];
        }
        acc += h[j] * (A + B + U * C + D);
    }
    return acc;
}

// full single-edge path (tail only)
__device__ __forceinline__ float one_edge(int e,
                                          const float* __restrict__ X,
                                          const float* __restrict__ EV,
                                          const int*   __restrict__ SRC,
                                          const float* __restrict__ W2r,
                                          const float* __restrict__ W1s) {
    int si = SRC[e];
    float ex = EV[3 * e], ey = EV[3 * e + 1], ez = EV[3 * e + 2];
    const float4* xp = (const float4*)(X + si * 32);
    float4 x[8];
#pragma unroll
    for (int k = 0; k < 8; ++k) x[k] = xp[k];
    float r = sqrtf(ex * ex + ey * ey + ez * ez);
    float ir = 1.0f / r;
    float ux = ex * ir, uy = ey * ir, uz = ez * ir;
    float U = ux + uy + uz;
    float h[HID];
    basis_h(r, W1s, h);
    return edge_acc(h, x, ux, uy, uz, U, W2r);
}

// Kernel B: two edges per thread; both edges' gathers issued up front so
// edge B's memory latency hides behind edge A's compute.
__global__ __launch_bounds__(256, 4) void edge_kernel(
    const float* __restrict__ X,     // N x 32
    const float* __restrict__ EV,    // E x 3
    const int*   __restrict__ SRC,   // E
    const float* __restrict__ W2r,   // 16 x 32 scaled
    const float* __restrict__ W1s,   // 10 x 16 scaled
    float* __restrict__ out, int E)
{
    int tid = threadIdx.x;
    int base = (blockIdx.x * 256 + tid) * 2;
    float contrib = 0.0f;
    if (base + 1 < E) {
        int2 sp = *(const int2*)(SRC + base);
        const float* evp = EV + 3 * base;   // base even -> 8B aligned
        float2 e01 = *(const float2*)(evp);
        float2 e23 = *(const float2*)(evp + 2);
        float2 e45 = *(const float2*)(evp + 4);
        const float4* xpA = (const float4*)(X + sp.x * 32);
        const float4* xpB = (const float4*)(X + sp.y * 32);
        float4 xA[8], xB[8];
#pragma unroll
        for (int k = 0; k < 8; ++k) xA[k] = xpA[k];
#pragma unroll
        for (int k = 0; k < 8; ++k) xB[k] = xpB[k];

        // edge A
        {
            float ex = e01.x, ey = e01.y, ez = e23.x;
            float r = sqrtf(ex * ex + ey * ey + ez * ez);
            float ir = 1.0f / r;
            float ux = ex * ir, uy = ey * ir, uz = ez * ir;
            float U = ux + uy + uz;
            float h[HID];
            basis_h(r, W1s, h);
            contrib = edge_acc(h, xA, ux, uy, uz, U, W2r);
        }
        // edge B
        {
            float ex = e23.y, ey = e45.x, ez = e45.y;
            float r = sqrtf(ex * ex + ey * ey + ez * ez);
            float ir = 1.0f / r;
            float ux = ex * ir, uy = ey * ir, uz = ez * ir;
            float U = ux + uy + uz;
            float h[HID];
            basis_h(r, W1s, h);
            contrib += edge_acc(h, xB, ux, uy, uz, U, W2r);
        }
    } else if (base < E) {
        contrib = one_edge(base, X, EV, SRC, W2r, W1s);
    }

    // wave64 shuffle reduce, cross-wave LDS reduce, one atomic per block
#pragma unroll
    for (int off = 32; off > 0; off >>= 1)
        contrib += __shfl_down(contrib, off, 64);
    __shared__ float wsum[4];
    int lane = tid & 63, w = tid >> 6;
    if (lane == 0) wsum[w] = contrib;
    __syncthreads();
    if (tid == 0) {
        float ssum = wsum[0] + wsum[1] + wsum[2] + wsum[3];
        atomicAdd(out, ssum);
    }
}

extern "C" void kernel_launch(void* const* d_in, const int* in_sizes, int n_in,
                              void* d_out, int out_size, void* d_ws, size_t ws_size,
                              hipStream_t stream) {
    const float* X   = (const float*)d_in[0];
    const float* EV  = (const float*)d_in[1];
    const float* W1  = (const float*)d_in[2];
    const float* W2  = (const float*)d_in[3];
    const int*   SRC = (const int*)d_in[4];
    int E = in_sizes[4];

    float* ws  = (float*)d_ws;   // 512 + 160 floats
    float* out = (float*)d_out;

    prep_kernel<<<1, 512, 0, stream>>>(W2, W1, ws, out);
    int pairs = (E + 1) / 2;
    int blocks = (pairs + 255) / 256;
    edge_kernel<<<blocks, 256, 0, stream>>>(X, EV, SRC, ws, ws + 512, out, E);
}